// Round 2
// baseline (12.818 us; speedup 1.0000x reference)
//
#include <hip/hip_runtime.h>

// NeRF ray rendering: R=1024 rays, N=576 samples (384 log inner + 192 outer).
// Outputs flat: image[1024*3] | invdepth[1024] | l_dist[1] = 4097 floats.
//
// One wave per ray. Two-level scan: 9 independent per-chunk (64-wide) scans
// done in parallel (ILP), then chunk carries combined with scalar chains.
// Distortion loss in O(N): sum_ij w_i w_j |t_i - t_j| = 2*sum_i w_i(t_i W_i - T_i)
// with W/T exclusive prefix sums (t sorted ascending).

#define NSAMP 576
#define NRAYS 1024
#define NCH 9

__device__ __forceinline__ float zexp(int i) {
    if (i < 384) return -1.2f + (float)i * (1.2f / 383.0f);
    return (float)(i - 384) * (2.0f / 191.0f);
}

__global__ __launch_bounds__(256) void render_kernel(
    const float* __restrict__ sigmas,   // [1024, 576]
    const float* __restrict__ rgbs,     // [1024, 576, 3]
    float* __restrict__ out,            // [4097]
    float* __restrict__ wsum)           // [1024] per-ray distortion (*2)
{
    const float L10 = 3.3219280948873623f;   // log2(10)
    const float LE  = 1.4426950408889634f;   // log2(e)
    const int lane = threadIdx.x & 63;
    const int ray  = blockIdx.x * 4 + (threadIdx.x >> 6);

    const float* __restrict__ sig = sigmas + (size_t)ray * NSAMP;
    const float* __restrict__ rgb = rgbs  + (size_t)ray * NSAMP * 3;

    float sg[NCH], r0[NCH], g0[NCH], b0[NCH];
    #pragma unroll
    for (int k = 0; k < NCH; ++k) {
        const int s = k * 64 + lane;
        sg[k] = sig[s];
        r0[k] = rgb[s * 3 + 0];
        g0[k] = rgb[s * 3 + 1];
        b0[k] = rgb[s * 3 + 2];
    }

    // geometry (pure ALU, overlaps the loads)
    float t[NCH], rz[NCH], p[NCH], al[NCH];
    #pragma unroll
    for (int k = 0; k < NCH; ++k) {
        const int s = k * 64 + lane;
        const float e0 = zexp(s);
        const float z  = exp2f(e0 * L10);
        rz[k] = exp2f(-e0 * L10);                      // 1/z
        t[k]  = (e0 + 1.2f) * (1.0f / 3.2f);
        const float dlt = (s == NSAMP - 1) ? 1e10f : (exp2f(zexp(s + 1) * L10) - z);
        const float e = exp2f(-sg[k] * dlt * LE);      // exp(-sigma*delta)
        al[k] = 1.0f - e;                              // alpha
        p[k]  = e + 1e-10f;                            // 1 - alpha + EPS
    }

    // 9 independent inclusive product scans, interleaved (6 dependent steps)
    #pragma unroll
    for (int off = 1; off < 64; off <<= 1) {
        float sh[NCH];
        #pragma unroll
        for (int k = 0; k < NCH; ++k) sh[k] = __shfl_up(p[k], off, 64);
        #pragma unroll
        for (int k = 0; k < NCH; ++k) if (lane >= off) p[k] *= sh[k];
    }

    // chunk totals + exclusive in-chunk prefix
    float tot[NCH], exP[NCH];
    #pragma unroll
    for (int k = 0; k < NCH; ++k) {
        tot[k] = __shfl(p[k], 63, 64);
        exP[k] = __shfl_up(p[k], 1, 64);
        if (lane == 0) exP[k] = 1.0f;
    }
    // cross-chunk carry: cP[k] = prod of totals 0..k-1 (scalar chain, 8 fmuls)
    float w[NCH];
    {
        float cP = 1.0f;
        #pragma unroll
        for (int k = 0; k < NCH; ++k) {
            w[k] = al[k] * cP * exP[k];
            cP *= tot[k];
        }
    }

    // 18 independent inclusive sum scans (w and w*t), interleaved
    float sw[NCH], st[NCH];
    #pragma unroll
    for (int k = 0; k < NCH; ++k) { sw[k] = w[k]; st[k] = w[k] * t[k]; }
    #pragma unroll
    for (int off = 1; off < 64; off <<= 1) {
        float a[NCH], b[NCH];
        #pragma unroll
        for (int k = 0; k < NCH; ++k) {
            a[k] = __shfl_up(sw[k], off, 64);
            b[k] = __shfl_up(st[k], off, 64);
        }
        #pragma unroll
        for (int k = 0; k < NCH; ++k)
            if (lane >= off) { sw[k] += a[k]; st[k] += b[k]; }
    }

    // accumulate outputs
    float imR = 0.f, imG = 0.f, imB = 0.f, invd = 0.f, dist = 0.f;
    {
        float cW = 0.f, cT = 0.f;
        #pragma unroll
        for (int k = 0; k < NCH; ++k) {
            const float wk = w[k];
            const float exW = cW + sw[k] - wk;            // exclusive prefix of w
            const float exT = cT + st[k] - wk * t[k];     // exclusive prefix of w*t
            dist += wk * (t[k] * exW - exT);
            imR  += wk * r0[k];
            imG  += wk * g0[k];
            imB  += wk * b0[k];
            invd += wk * rz[k];
            cW += __shfl(sw[k], 63, 64);
            cT += __shfl(st[k], 63, 64);
        }
    }

    #pragma unroll
    for (int off = 32; off; off >>= 1) {
        imR  += __shfl_down(imR,  off, 64);
        imG  += __shfl_down(imG,  off, 64);
        imB  += __shfl_down(imB,  off, 64);
        invd += __shfl_down(invd, off, 64);
        dist += __shfl_down(dist, off, 64);
    }

    if (lane == 0) {
        out[ray * 3 + 0] = imR;
        out[ray * 3 + 1] = imG;
        out[ray * 3 + 2] = imB;
        out[3 * NRAYS + ray] = invd;
        wsum[ray] = 2.0f * dist;
    }
}

__global__ __launch_bounds__(64) void reduce_kernel(
    const float* __restrict__ wsum, float* __restrict__ out)
{
    const int lane = threadIdx.x;
    float v = 0.f;
    #pragma unroll
    for (int j = 0; j < 16; ++j) v += wsum[lane + 64 * j];
    #pragma unroll
    for (int off = 32; off; off >>= 1) v += __shfl_down(v, off, 64);
    if (lane == 0) out[3 * NRAYS + NRAYS] = v * (1.0f / 1024.0f);
}

extern "C" void kernel_launch(void* const* d_in, const int* in_sizes, int n_in,
                              void* d_out, int out_size, void* d_ws, size_t ws_size,
                              hipStream_t stream) {
    const float* sigmas = (const float*)d_in[0];
    const float* rgbs   = (const float*)d_in[1];
    float* out = (float*)d_out;
    float* ws  = (float*)d_ws;

    render_kernel<<<NRAYS / 4, 256, 0, stream>>>(sigmas, rgbs, out, ws);
    reduce_kernel<<<1, 64, 0, stream>>>(ws, out);
}

// Round 3
// 11.584 us; speedup vs baseline: 1.1065x; 1.1065x over previous
//
#include <hip/hip_runtime.h>

// NeRF ray rendering: R=1024 rays, N=576 samples. Outputs:
// image[1024*3] | invdepth[1024] | l_dist[1] = 4097 floats.
//
// One wave per ray, LANE-SERIAL decomposition: lane l owns samples
// [9l, 9l+9). Per-lane serial cumprod/cumsum (VALU chains, no shuffles);
// wave-level scans only over the 64 lane totals. Distortion via
// single-scan identity: sum_i w_i t_i (2*W_i_ex + w_i - S_w).
// Inputs staged coalesced (float4) through LDS, read back per-lane
// (bank strides 9/27 are odd -> 2-way conflict, free).

#define NSAMP 576
#define NRAYS 1024
#define RPB 4          // rays (waves) per block

__device__ __forceinline__ float zexp(int i) {
    if (i < 384) return -1.2f + (float)i * (1.2f / 383.0f);
    return (float)(i - 384) * (2.0f / 191.0f);
}

__global__ __launch_bounds__(256) void render_kernel(
    const float* __restrict__ sigmas,   // [1024, 576]
    const float* __restrict__ rgbs,     // [1024, 576, 3]
    float* __restrict__ out,            // [4097]
    float* __restrict__ wsum)           // [1024]
{
    const float L10 = 3.3219280948873623f;   // log2(10)
    const float LE  = 1.4426950408889634f;   // log2(e)
    __shared__ float lds[RPB * 2304];        // per ray: 576 sig + 1728 rgb

    const int lane = threadIdx.x & 63;
    const int wid  = threadIdx.x >> 6;
    const int ray  = blockIdx.x * RPB + wid;
    float* my = lds + wid * 2304;

    // ---- stage: coalesced float4 global -> linear LDS ----
    const float4* sig4 = (const float4*)(sigmas + (size_t)ray * NSAMP);
    const float4* rgb4 = (const float4*)(rgbs  + (size_t)ray * NSAMP * 3);
    float4* ls = (float4*)my;            // 144 float4 of sigma
    float4* lr = (float4*)(my + NSAMP);  // 432 float4 of rgb

    float4 s0 = sig4[lane];
    float4 s1 = sig4[64 + lane];
    float4 s2; if (lane < 16) s2 = sig4[128 + lane];
    float4 r0 = rgb4[lane],        r1 = rgb4[64 + lane],  r2 = rgb4[128 + lane];
    float4 r3 = rgb4[192 + lane],  r4 = rgb4[256 + lane], r5 = rgb4[320 + lane];
    float4 r6; if (lane < 48) r6 = rgb4[384 + lane];

    ls[lane] = s0; ls[64 + lane] = s1; if (lane < 16) ls[128 + lane] = s2;
    lr[lane] = r0; lr[64 + lane] = r1; lr[128 + lane] = r2;
    lr[192 + lane] = r3; lr[256 + lane] = r4; lr[320 + lane] = r5;
    if (lane < 48) lr[384 + lane] = r6;
    __syncthreads();

    // ---- per-lane geometry + alpha ----
    const int sbase = lane * 9;
    float z[10];
    #pragma unroll
    for (int j = 0; j < 10; ++j) z[j] = exp2f(zexp(sbase + j) * L10);

    float om[9], al[9], t[9], rz[9];
    float Pin = 1.0f;
    #pragma unroll
    for (int j = 0; j < 9; ++j) {
        const int s = sbase + j;
        const float e0 = zexp(s);
        t[j]  = (e0 + 1.2f) * (1.0f / 3.2f);
        rz[j] = exp2f(-e0 * L10);
        const float dlt = (s == NSAMP - 1) ? 1e10f : (z[j + 1] - z[j]);
        const float sg = my[s - sbase + sbase];  // my[s]
        const float e = exp2f(-my[s] * dlt * LE);
        (void)sg;
        al[j] = 1.0f - e;
        om[j] = e + 1e-10f;
        Pin *= om[j];
    }

    // ---- wave scan #1: inclusive product of lane totals ----
    float inc = Pin;
    #pragma unroll
    for (int off = 1; off < 64; off <<= 1) {
        float o = __shfl_up(inc, off, 64);
        if (lane >= off) inc *= o;
    }
    float Tcar = __shfl_up(inc, 1, 64);
    if (lane == 0) Tcar = 1.0f;

    // ---- per-lane weights + accumulators ----
    float w[9];
    float swl = 0.f, imR = 0.f, imG = 0.f, imB = 0.f, invd = 0.f;
    {
        float cur = Tcar;
        #pragma unroll
        for (int j = 0; j < 9; ++j) {
            const int s = sbase + j;
            const float wk = al[j] * cur;
            cur *= om[j];
            w[j] = wk;
            swl += wk;
            imR += wk * my[NSAMP + s * 3 + 0];
            imG += wk * my[NSAMP + s * 3 + 1];
            imB += wk * my[NSAMP + s * 3 + 2];
            invd += wk * rz[j];
        }
    }

    // ---- wave scan #2: inclusive sum of lane w-totals ----
    float incs = swl;
    #pragma unroll
    for (int off = 1; off < 64; off <<= 1) {
        float a = __shfl_up(incs, off, 64);
        if (lane >= off) incs += a;
    }
    const float Sw = __shfl(incs, 63, 64);
    float runW = incs - swl;   // exclusive lane prefix of w

    float dist = 0.f;
    #pragma unroll
    for (int j = 0; j < 9; ++j) {
        dist += w[j] * t[j] * (2.0f * runW + w[j] - Sw);
        runW += w[j];
    }

    // ---- final 5-value wave reduce ----
    #pragma unroll
    for (int off = 32; off; off >>= 1) {
        imR  += __shfl_down(imR,  off, 64);
        imG  += __shfl_down(imG,  off, 64);
        imB  += __shfl_down(imB,  off, 64);
        invd += __shfl_down(invd, off, 64);
        dist += __shfl_down(dist, off, 64);
    }

    if (lane == 0) {
        out[ray * 3 + 0] = imR;
        out[ray * 3 + 1] = imG;
        out[ray * 3 + 2] = imB;
        out[3 * NRAYS + ray] = invd;
        wsum[ray] = 2.0f * dist;
    }
}

__global__ __launch_bounds__(64) void reduce_kernel(
    const float* __restrict__ wsum, float* __restrict__ out)
{
    const int lane = threadIdx.x;
    const float4* w4 = (const float4*)wsum;
    float4 a = w4[lane], b = w4[64 + lane], c = w4[128 + lane], d = w4[192 + lane];
    float v = (a.x + a.y + a.z + a.w) + (b.x + b.y + b.z + b.w)
            + (c.x + c.y + c.z + c.w) + (d.x + d.y + d.z + d.w);
    #pragma unroll
    for (int off = 32; off; off >>= 1) v += __shfl_down(v, off, 64);
    if (lane == 0) out[3 * NRAYS + NRAYS] = v * (1.0f / 1024.0f);
}

extern "C" void kernel_launch(void* const* d_in, const int* in_sizes, int n_in,
                              void* d_out, int out_size, void* d_ws, size_t ws_size,
                              hipStream_t stream) {
    const float* sigmas = (const float*)d_in[0];
    const float* rgbs   = (const float*)d_in[1];
    float* out = (float*)d_out;
    float* ws  = (float*)d_ws;

    render_kernel<<<NRAYS / RPB, 256, 0, stream>>>(sigmas, rgbs, out, ws);
    reduce_kernel<<<1, 64, 0, stream>>>(ws, out);
}